// Round 12
// baseline (23.744 us; speedup 1.0000x reference)
//
#include <hip/hip_runtime.h>
#include <math.h>

#define L_SEQ 4096   // sequence length L
#define NT 512       // threads per block (one block per sequence)
#define CHUNK 8      // elements per thread
#define NW (NT/64)   // waves per block (8)

typedef float f2 __attribute__((ext_vector_type(2)));

__device__ __forceinline__ f2 mkf2(float a, float b) { f2 r; r.x = a; r.y = b; return r; }
__device__ __forceinline__ f2 max2(f2 a, f2 b) { return mkf2(fmaxf(a.x, b.x), fmaxf(a.y, b.y)); }
__device__ __forceinline__ float hmax(f2 v) { return fmaxf(v.x, v.y); }

struct M2 { f2 r0, r1; };   // rows: r0=(a00,a01), r1=(a10,a11)

// max-plus 2x2 compose: C[s][t] = max_k(A[s][k] + B[k][t])  (packed rows)
__device__ __forceinline__ M2 mpc(const M2& A, const M2& B) {
  M2 C;
  C.r0 = max2(mkf2(A.r0.x, A.r0.x) + B.r0, mkf2(A.r0.y, A.r0.y) + B.r1);
  C.r1 = max2(mkf2(A.r1.x, A.r1.x) + B.r0, mkf2(A.r1.y, A.r1.y) + B.r1);
  return C;
}
// row-vector max-plus apply: r[t] = max_s(v[s] + M[s][t])
__device__ __forceinline__ f2 mapply(f2 v, const M2& M) {
  return max2(mkf2(v.x, v.x) + M.r0, mkf2(v.y, v.y) + M.r1);
}
__device__ __forceinline__ f2 colmax(const M2& M) { return max2(M.r0, M.r1); }

__device__ __forceinline__ M2 ld4(float4 v) { M2 M; M.r0 = mkf2(v.x, v.y); M.r1 = mkf2(v.z, v.w); return M; }
__device__ __forceinline__ float4 st4(const M2& M) { return make_float4(M.r0.x, M.r0.y, M.r1.x, M.r1.y); }

// DPP with explicit `old`: lanes masked off by row_mask, or reading an
// out-of-range source with bound_ctrl=false, KEEP `old`. This encodes the
// scan's lane conditions in hardware — no cndmask, no exec games.
// ctrl: 0x110+N = row_shr:N, 0x142 = row_bcast:15, 0x143 = row_bcast:31,
// 0x138 = wave_shr:1.
template <int CTRL, int RMASK>
__device__ __forceinline__ float dppo(float old, float x) {
  return __int_as_float(__builtin_amdgcn_update_dpp(
      __float_as_int(old), __float_as_int(x), CTRL, RMASK, 0xf, false));
}
// identity-filled matrix fetch: inactive lanes see max-plus identity
// [[0,-inf],[-inf,0]], so the unconditional compose is a no-op there.
template <int CTRL, int RMASK>
__device__ __forceinline__ M2 dppI(const M2& x) {
  M2 r;
  r.r0.x = dppo<CTRL, RMASK>(0.f,       x.r0.x);
  r.r0.y = dppo<CTRL, RMASK>(-INFINITY, x.r0.y);
  r.r1.x = dppo<CTRL, RMASK>(-INFINITY, x.r1.x);
  r.r1.y = dppo<CTRL, RMASK>(0.f,       x.r1.y);
  return r;
}
__device__ __forceinline__ float rdl(float x, int l) {
  return __int_as_float(__builtin_amdgcn_readlane(__float_as_int(x), l));
}

__global__ __launch_bounds__(NT, 8) void chain_fb_kernel(
    const float* __restrict__ jp, const float* __restrict__ bp,
    const int* __restrict__ obs, float* __restrict__ out) {
  __shared__ float4 T4s[16];             // 4-bit-pattern transforms
  __shared__ f2 T8r0[256], T8r1[256];    // 8-bit LUT rows (4 KB)
  __shared__ float4 wtf[NW];             // fwd wave totals
  __shared__ float4 wtbr[NW];            // bwd wave totals, REVERSED slot order

  const int t = threadIdx.x;
  const int lane = t & 63;
  const int w = t >> 6;
  const long b = blockIdx.x;

  const float P   = 0.25f * jp[0];   // psi = [[P,-P],[-P,P]]
  const float hb0 = 0.5f * bp[0];    // u_i = 0.5*b[obs_i]; phi_i = (-u, +u)
  const float hb1 = 0.5f * bp[1];

  // ---- issue obs loads first (latency hidden under LUT build)
  const int4* rowp = (const int4*)(obs + b * L_SEQ + (long)t * CHUNK);
  int4 q0 = rowp[0], q1 = rowp[1];

  // ---- build LUT: pattern p -> E(p0)(*)E(p1)(*)... (bit 0 = earliest elem)
  //      E(u): r0 = (P-u, -u-P), r1 = (u-P, u+P)
  if (t < 16) {
    float u0 = (t & 1) ? hb1 : hb0;
    M2 Tt; Tt.r0 = mkf2(P - u0, -u0 - P); Tt.r1 = mkf2(u0 - P, u0 + P);
    #pragma unroll
    for (int k = 1; k < 4; ++k) {
      float uk = ((t >> k) & 1) ? hb1 : hb0;
      M2 Ek; Ek.r0 = mkf2(P - uk, -uk - P); Ek.r1 = mkf2(uk - P, uk + P);
      Tt = mpc(Tt, Ek);
    }
    T4s[t] = st4(Tt);
  }
  __syncthreads();
  if (t < 256) {  // T8[p] = T4[p&15] (*) T4[p>>4]
    M2 M = mpc(ld4(T4s[t & 15]), ld4(T4s[(t >> 4) & 15]));
    T8r0[t] = M.r0; T8r1[t] = M.r1;
  }
  // pack obs bit mask while the barrier drains
  const unsigned m =
      (unsigned)(q0.x & 1)       | (unsigned)(q0.y & 1) << 1 |
      (unsigned)(q0.z & 1) << 2  | (unsigned)(q0.w & 1) << 3 |
      (unsigned)(q1.x & 1) << 4  | (unsigned)(q1.y & 1) << 5 |
      (unsigned)(q1.z & 1) << 6  | (unsigned)(q1.w & 1) << 7;
  __syncthreads();

  // ---- chunk transforms: fwd for own chunk; bwd for MIRRORED chunk (v-space)
  const unsigned mrev = (unsigned)__shfl((int)m, 63 - lane);
  const unsigned r = __brev(mrev) >> 24;
  M2 T;  T.r0  = T8r0[m]; T.r1  = T8r1[m];   // fwd: E(u0)(*)...(*)E(u7)
  M2 Rv; Rv.r0 = T8r0[r]; Rv.r1 = T8r1[r];   // bwd of chunk 63-lane

  // ---- dual Hillis-Steele inclusive scans, conditions encoded in DPP
  T  = mpc(dppI<0x111, 0xf>(T),  T);   Rv = mpc(dppI<0x111, 0xf>(Rv), Rv);
  T  = mpc(dppI<0x112, 0xf>(T),  T);   Rv = mpc(dppI<0x112, 0xf>(Rv), Rv);
  T  = mpc(dppI<0x114, 0xf>(T),  T);   Rv = mpc(dppI<0x114, 0xf>(Rv), Rv);
  T  = mpc(dppI<0x118, 0xf>(T),  T);   Rv = mpc(dppI<0x118, 0xf>(Rv), Rv);
  T  = mpc(dppI<0x142, 0xa>(T),  T);   Rv = mpc(dppI<0x142, 0xa>(Rv), Rv);
  T  = mpc(dppI<0x143, 0xc>(T),  T);   Rv = mpc(dppI<0x143, 0xc>(Rv), Rv);

  if (lane == 63) { wtf[w] = st4(T); wtbr[7 - w] = st4(Rv); }

  __syncthreads();  // wave totals visible

  // ---- cross-wave tail: 8-lane DPP mini-scan of wave totals (lanes 0-7
  //      valid; higher-lane replicas unused), wave-uniform msg via readlane.
  M2 Xf = ld4(wtf[lane & 7]);
  M2 Xb = ld4(wtbr[lane & 7]);
  Xf = mpc(dppI<0x111, 0xf>(Xf), Xf);  Xb = mpc(dppI<0x111, 0xf>(Xb), Xb);
  Xf = mpc(dppI<0x112, 0xf>(Xf), Xf);  Xb = mpc(dppI<0x112, 0xf>(Xb), Xb);
  Xf = mpc(dppI<0x114, 0xf>(Xf), Xf);  Xb = mpc(dppI<0x114, 0xf>(Xb), Xb);
  const f2 Vf = colmax(Xf);   // lane l: msg after waves 0..l
  const f2 Vb = colmax(Xb);   // lane l: msg after waves 7..7-l (bwd)

  f2 v, vb;   // wave-incoming messages (wave-uniform)
  if (w > 0) v = mkf2(rdl(Vf.x, w - 1), rdl(Vf.y, w - 1));
  else       v = mkf2(0.f, 0.f);
  if (w < 7) vb = mkf2(rdl(Vb.x, 6 - w), rdl(Vb.y, 6 - w));
  else       vb = mkf2(0.f, 0.f);

  // per-lane exclusive messages: apply v through own inclusive scan, shift
  // down one lane; lane 0 keeps `old` = wave-incoming (bound_ctrl=false).
  f2 wv  = mapply(v,  T);
  f2 wvb = mapply(vb, Rv);
  f2 fm, bmv;
  fm.x  = dppo<0x138, 0xf>(v.x,  wv.x);
  fm.y  = dppo<0x138, 0xf>(v.y,  wv.y);
  bmv.x = dppo<0x138, 0xf>(vb.x, wvb.x);
  bmv.y = dppo<0x138, 0xf>(vb.y, wvb.y);
  // bwd message computed at v-lane (63-lane): mirror back
  f2 bm = mkf2(__shfl(bmv.x, 63 - lane), __shfl(bmv.y, 63 - lane));

  // ---- replay (packed): xy = (phi0+msg0, phi1+msg1)
  const f2 pp  = mkf2(P, -P), pm = mkf2(-P, P);
  const f2 uvl = mkf2(-hb0, hb0), uvh = mkf2(-hb1, hb1);
  f2 o[CHUNK];
  #pragma unroll
  for (int e = 0; e < CHUNK; ++e) {
    f2 uv = ((m >> e) & 1) ? uvh : uvl;
    f2 xy = fm + uv;
    o[e] = xy;
    fm = mkf2(hmax(xy + pp), hmax(xy + pm));
  }
  #pragma unroll
  for (int e = CHUNK - 1; e >= 0; --e) {
    f2 uv = ((m >> e) & 1) ? uvh : uvl;
    o[e] += bm;
    f2 xy = bm + uv;
    bm = mkf2(hmax(xy + pp), hmax(xy + pm));
  }

  // ---- store: contiguous 8 floats per state row (coalesced float4s)
  const long base = (long)t * CHUNK;
  float* r0 = out + b * (2L * L_SEQ) + base;   // out[b][0][base..]
  float* r1 = r0 + L_SEQ;                      // out[b][1][base..]
  ((float4*)r0)[0] = make_float4(o[0].x, o[1].x, o[2].x, o[3].x);
  ((float4*)r0)[1] = make_float4(o[4].x, o[5].x, o[6].x, o[7].x);
  ((float4*)r1)[0] = make_float4(o[0].y, o[1].y, o[2].y, o[3].y);
  ((float4*)r1)[1] = make_float4(o[4].y, o[5].y, o[6].y, o[7].y);
}

extern "C" void kernel_launch(void* const* d_in, const int* in_sizes, int n_in,
                              void* d_out, int out_size, void* d_ws, size_t ws_size,
                              hipStream_t stream) {
  const float* jp  = (const float*)d_in[0];
  const float* bp  = (const float*)d_in[1];
  const int*   obs = (const int*)d_in[2];
  float* out = (float*)d_out;
  const int B = in_sizes[2] / L_SEQ;   // 2048
  chain_fb_kernel<<<B, NT, 0, stream>>>(jp, bp, obs, out);
}

// Round 13
// 23.230 us; speedup vs baseline: 1.0221x; 1.0221x over previous
//
#include <hip/hip_runtime.h>
#include <math.h>

#define L_SEQ 4096   // sequence length L
#define NT 512       // threads per block (one block per sequence)
#define CHUNK 8      // elements per thread
#define NW (NT/64)   // waves per block (8)

typedef float f2 __attribute__((ext_vector_type(2)));

__device__ __forceinline__ f2 mkf2(float a, float b) { f2 r; r.x = a; r.y = b; return r; }
__device__ __forceinline__ f2 max2(f2 a, f2 b) { return mkf2(fmaxf(a.x, b.x), fmaxf(a.y, b.y)); }
__device__ __forceinline__ float hmax(f2 v) { return fmaxf(v.x, v.y); }

struct M2 { f2 r0, r1; };   // rows: r0=(a00,a01), r1=(a10,a11)

// max-plus 2x2 compose: C[s][t] = max_k(A[s][k] + B[k][t])  (packed rows)
__device__ __forceinline__ M2 mpc(const M2& A, const M2& B) {
  M2 C;
  C.r0 = max2(mkf2(A.r0.x, A.r0.x) + B.r0, mkf2(A.r0.y, A.r0.y) + B.r1);
  C.r1 = max2(mkf2(A.r1.x, A.r1.x) + B.r0, mkf2(A.r1.y, A.r1.y) + B.r1);
  return C;
}
// row-vector max-plus apply: r[t] = max_s(v[s] + M[s][t])
__device__ __forceinline__ f2 mapply(f2 v, const M2& M) {
  return max2(mkf2(v.x, v.x) + M.r0, mkf2(v.y, v.y) + M.r1);
}
__device__ __forceinline__ f2 colmax(const M2& M) { return max2(M.r0, M.r1); }

__device__ __forceinline__ M2 ld4(float4 v) { M2 M; M.r0 = mkf2(v.x, v.y); M.r1 = mkf2(v.z, v.w); return M; }
__device__ __forceinline__ float4 st4(const M2& M) { return make_float4(M.r0.x, M.r0.y, M.r1.x, M.r1.y); }

// DPP cross-lane fetch (VALU pipe). 0x110+N = row_shr:N, 0x142 = row_bcast:15,
// 0x143 = row_bcast:31, 0x138 = wave_shr:1 (crosses rows, lane0 keeps old/0).
template <int CTRL>
__device__ __forceinline__ float dppf(float x) {
  return __int_as_float(__builtin_amdgcn_update_dpp(
      0, __float_as_int(x), CTRL, 0xf, 0xf, true));
}
template <int CTRL>
__device__ __forceinline__ f2 dpp2(f2 x) { return mkf2(dppf<CTRL>(x.x), dppf<CTRL>(x.y)); }
template <int CTRL>
__device__ __forceinline__ M2 dpp_fetch(const M2& x) {
  M2 r; r.r0 = dpp2<CTRL>(x.r0); r.r1 = dpp2<CTRL>(x.r1); return r;
}
__device__ __forceinline__ float rdl(float x, int l) {
  return __int_as_float(__builtin_amdgcn_readlane(__float_as_int(x), l));
}

__global__ __launch_bounds__(NT, 8) void chain_fb_kernel(
    const float* __restrict__ jp, const float* __restrict__ bp,
    const int* __restrict__ obs, float* __restrict__ out) {
  __shared__ float4 T4s[16];             // 4-bit-pattern transforms
  __shared__ f2 T8r0[256], T8r1[256];    // 8-bit LUT rows (4 KB)
  __shared__ float4 wtf[NW];             // fwd wave totals
  __shared__ float4 wtbr[NW];            // bwd wave totals, REVERSED slot order

  const int t = threadIdx.x;
  const int lane = t & 63;
  const int w = t >> 6;
  const long b = blockIdx.x;

  const float P   = 0.25f * jp[0];   // psi = [[P,-P],[-P,P]]
  const float hb0 = 0.5f * bp[0];    // u_i = 0.5*b[obs_i]; phi_i = (-u, +u)
  const float hb1 = 0.5f * bp[1];

  // ---- issue obs loads first (latency hidden under LUT build)
  const int4* rowp = (const int4*)(obs + b * L_SEQ + (long)t * CHUNK);
  int4 q0 = rowp[0], q1 = rowp[1];

  // ---- build LUT: pattern p -> E(p0)(*)E(p1)(*)... (bit 0 = earliest elem)
  //      E(u): r0 = (P-u, -u-P), r1 = (u-P, u+P)
  if (t < 16) {
    float u0 = (t & 1) ? hb1 : hb0;
    M2 Tt; Tt.r0 = mkf2(P - u0, -u0 - P); Tt.r1 = mkf2(u0 - P, u0 + P);
    #pragma unroll
    for (int k = 1; k < 4; ++k) {
      float uk = ((t >> k) & 1) ? hb1 : hb0;
      M2 Ek; Ek.r0 = mkf2(P - uk, -uk - P); Ek.r1 = mkf2(uk - P, uk + P);
      Tt = mpc(Tt, Ek);
    }
    T4s[t] = st4(Tt);
  }
  __syncthreads();
  if (t < 256) {  // T8[p] = T4[p&15] (*) T4[p>>4]
    M2 M = mpc(ld4(T4s[t & 15]), ld4(T4s[(t >> 4) & 15]));
    T8r0[t] = M.r0; T8r1[t] = M.r1;
  }
  // pack obs bit mask while the barrier drains
  const unsigned m =
      (unsigned)(q0.x & 1)       | (unsigned)(q0.y & 1) << 1 |
      (unsigned)(q0.z & 1) << 2  | (unsigned)(q0.w & 1) << 3 |
      (unsigned)(q1.x & 1) << 4  | (unsigned)(q1.y & 1) << 5 |
      (unsigned)(q1.z & 1) << 6  | (unsigned)(q1.w & 1) << 7;
  __syncthreads();

  // ---- chunk transforms: fwd for own chunk; bwd for MIRRORED chunk (v-space)
  const unsigned mrev = (unsigned)__shfl((int)m, 63 - lane);
  const unsigned r = __brev(mrev) >> 24;
  M2 T;  T.r0  = T8r0[m]; T.r1  = T8r1[m];   // fwd: E(u0)(*)...(*)E(u7)
  M2 Rv; Rv.r0 = T8r0[r]; Rv.r1 = T8r1[r];   // bwd of chunk 63-lane

  // ---- dual Hillis-Steele inclusive scans via DPP (VALU pipe)
  {
    M2 f, g;
    f = dpp_fetch<0x111>(T); g = dpp_fetch<0x111>(Rv);           // row_shr:1
    if ((lane & 15) >= 1) { T = mpc(f, T); Rv = mpc(g, Rv); }
    f = dpp_fetch<0x112>(T); g = dpp_fetch<0x112>(Rv);           // row_shr:2
    if ((lane & 15) >= 2) { T = mpc(f, T); Rv = mpc(g, Rv); }
    f = dpp_fetch<0x114>(T); g = dpp_fetch<0x114>(Rv);           // row_shr:4
    if ((lane & 15) >= 4) { T = mpc(f, T); Rv = mpc(g, Rv); }
    f = dpp_fetch<0x118>(T); g = dpp_fetch<0x118>(Rv);           // row_shr:8
    if ((lane & 15) >= 8) { T = mpc(f, T); Rv = mpc(g, Rv); }
    f = dpp_fetch<0x142>(T); g = dpp_fetch<0x142>(Rv);           // row_bcast:15
    if (lane & 16)        { T = mpc(f, T); Rv = mpc(g, Rv); }
    f = dpp_fetch<0x143>(T); g = dpp_fetch<0x143>(Rv);           // row_bcast:31
    if (lane >= 32)       { T = mpc(f, T); Rv = mpc(g, Rv); }
  }
  if (lane == 63) { wtf[w] = st4(T); wtbr[7 - w] = st4(Rv); }

  __syncthreads();  // wave totals visible

  // ---- cross-wave tail: 8-lane DPP mini-scan of wave totals (lanes 0-7
  //      valid; higher-lane replicas unused), wave-uniform msg via readlane.
  M2 Xf = ld4(wtf[lane & 7]);
  M2 Xb = ld4(wtbr[lane & 7]);
  {
    M2 f, g;
    f = dpp_fetch<0x111>(Xf); g = dpp_fetch<0x111>(Xb);
    if ((lane & 15) >= 1) { Xf = mpc(f, Xf); Xb = mpc(g, Xb); }
    f = dpp_fetch<0x112>(Xf); g = dpp_fetch<0x112>(Xb);
    if ((lane & 15) >= 2) { Xf = mpc(f, Xf); Xb = mpc(g, Xb); }
    f = dpp_fetch<0x114>(Xf); g = dpp_fetch<0x114>(Xb);
    if ((lane & 15) >= 4) { Xf = mpc(f, Xf); Xb = mpc(g, Xb); }
  }
  const f2 Vf = colmax(Xf);   // lane l: msg after waves 0..l
  const f2 Vb = colmax(Xb);   // lane l: msg after waves 7..7-l (bwd)

  f2 v, vb;   // wave-incoming messages (wave-uniform)
  if (w > 0) v = mkf2(rdl(Vf.x, w - 1), rdl(Vf.y, w - 1));
  else       v = mkf2(0.f, 0.f);
  if (w < 7) vb = mkf2(rdl(Vb.x, 6 - w), rdl(Vb.y, 6 - w));
  else       vb = mkf2(0.f, 0.f);

  // per-lane exclusive messages: apply v through own inclusive scan, shift
  // down one lane (wave_shr:1); lane 0 = wave-incoming.
  f2 wv  = mapply(v,  T);
  f2 wvb = mapply(vb, Rv);
  f2 fm  = dpp2<0x138>(wv);
  f2 bmv = dpp2<0x138>(wvb);
  if (lane == 0) { fm = v; bmv = vb; }
  // bwd message computed at v-lane (63-lane): mirror back
  f2 bm = mkf2(__shfl(bmv.x, 63 - lane), __shfl(bmv.y, 63 - lane));

  // ---- hoisted per-element phi vectors: uv[e] = (-u_e, +u_e), selected once
  f2 uv[CHUNK];
  #pragma unroll
  for (int e = 0; e < CHUNK; ++e) {
    float u = ((m >> e) & 1) ? hb1 : hb0;
    uv[e] = mkf2(-u, u);
  }

  const f2 pp = mkf2(P, -P), pm = mkf2(-P, P);
  const long base = (long)t * CHUNK;
  float* r0 = out + b * (2L * L_SEQ) + base;   // out[b][0][base..]
  float* r1 = r0 + L_SEQ;                      // out[b][1][base..]

  // ---- fwd replay: o = phi + fwd  (xy is exactly phi+msg)
  f2 o[CHUNK];
  #pragma unroll
  for (int e = 0; e < CHUNK; ++e) {
    f2 xy = fm + uv[e];
    o[e] = xy;
    fm = mkf2(hmax(xy + pp), hmax(xy + pm));
  }
  // ---- bwd replay (right->left), stores emitted per half as it completes
  #pragma unroll
  for (int e = CHUNK - 1; e >= 0; --e) {
    o[e] += bm;
    f2 xy = bm + uv[e];
    bm = mkf2(hmax(xy + pp), hmax(xy + pm));
    if (e == 4) {   // elements 4..7 final: start the write drain early
      ((float4*)r0)[1] = make_float4(o[4].x, o[5].x, o[6].x, o[7].x);
      ((float4*)r1)[1] = make_float4(o[4].y, o[5].y, o[6].y, o[7].y);
    }
  }
  ((float4*)r0)[0] = make_float4(o[0].x, o[1].x, o[2].x, o[3].x);
  ((float4*)r1)[0] = make_float4(o[0].y, o[1].y, o[2].y, o[3].y);
}

extern "C" void kernel_launch(void* const* d_in, const int* in_sizes, int n_in,
                              void* d_out, int out_size, void* d_ws, size_t ws_size,
                              hipStream_t stream) {
  const float* jp  = (const float*)d_in[0];
  const float* bp  = (const float*)d_in[1];
  const int*   obs = (const int*)d_in[2];
  float* out = (float*)d_out;
  const int B = in_sizes[2] / L_SEQ;   // 2048
  chain_fb_kernel<<<B, NT, 0, stream>>>(jp, bp, obs, out);
}